// Round 4
// baseline (165.022 us; speedup 1.0000x reference)
//
#include <hip/hip_runtime.h>
#include <stdint.h>

#define EPSN 1e-12f

typedef float f32x4 __attribute__((ext_vector_type(4)));
typedef __bf16 bf16x8 __attribute__((ext_vector_type(8)));

// ---- bf16 helpers (round-to-nearest-even) ----
__device__ __forceinline__ unsigned short f2bf(float f) {
  union { float f; unsigned int u; } v; v.f = f;
  unsigned int u = v.u + 0x7FFFu + ((v.u >> 16) & 1u);
  return (unsigned short)(u >> 16);
}

// ---- workspace layout (ushort offsets) ----
// wqP: bf16 [1024][288]  (k 0..257 = weights, 258 = bias, 259.. = 0)
// wkP: bf16 [1024][288]
// wvP: bf16 [256][64]    WVt[o][m] = sum_f wout[o][f] * v[m][f]
#define WQP_OFF 0
#define WKP_OFF (1024 * 288)
#define WVP_OFF (2 * 1024 * 288)

// =====================================================================
// prep: pack weights to bf16 (padded, bias-folded) + fuse v@wout^T
// blocks [0,1152): transpose/pack.  blocks [1152,1408): WVt, 4 lanes
// per (o,m) with quad-shuffle reduce (avoids 256-deep unrolled chain).
// =====================================================================
__global__ __launch_bounds__(256) void prep_kernel(
    const float* __restrict__ wq, const float* __restrict__ bq,
    const float* __restrict__ wk, const float* __restrict__ bk,
    const float* __restrict__ v, const float* __restrict__ wout,
    unsigned short* __restrict__ wsp) {
  if (blockIdx.x < 1152) {
    int idx = blockIdx.x * 256 + threadIdx.x;
    if (idx < 1024 * 288) {
      int o = idx / 288, k = idx - o * 288;
      float vq, vk;
      if (k < 258)      { vq = wq[o * 258 + k]; vk = wk[o * 258 + k]; }
      else if (k == 258){ vq = bq[o];           vk = bk[o]; }
      else              { vq = 0.f;             vk = 0.f; }
      wsp[WQP_OFF + idx] = f2bf(vq);
      wsp[WKP_OFF + idx] = f2bf(vk);
    }
  } else {
    int idx2 = (blockIdx.x - 1152) * 256 + threadIdx.x;  // [0, 65536)
    int fc = idx2 & 3, m = (idx2 >> 2) & 63, o = idx2 >> 8;
    const f32x4* wo = (const f32x4*)(wout + o * 256 + fc * 64);
    const f32x4* vm = (const f32x4*)(v + m * 256 + fc * 64);
    float s = 0.f;
#pragma unroll
    for (int f = 0; f < 16; ++f) {
      f32x4 a = wo[f], bvv = vm[f];
      s += a[0]*bvv[0] + a[1]*bvv[1] + a[2]*bvv[2] + a[3]*bvv[3];
    }
    s += __shfl_xor(s, 1, 64);
    s += __shfl_xor(s, 2, 64);
    if (fc == 0) wsp[WVP_OFF + o * 64 + m] = f2bf(s);
  }
}

// =====================================================================
// fused: stage xp -> q MFMA -> norm/qbar -> k MFMA -> attn -> epilogue MFMA
// TILE_P = 32 pixels/block, grid 512 -> 2 blocks/CU co-resident
// block = 1024 threads (16 waves); wave w: o-range [w*64, w*64+64)
// =====================================================================
#define KP 296   // xp row stride in bf16 (16B-aligned rows for ds_read_b128)
#define QS 34    // qbar row stride (floats)

__global__ __launch_bounds__(1024) void fused_kernel(
    const float* __restrict__ x, const float* __restrict__ pos,
    const unsigned short* __restrict__ wsp, const float* __restrict__ bout,
    float* __restrict__ out) {
  __shared__ __align__(16) unsigned short xp[32 * KP];     // 18944 B
  __shared__ __align__(16) float qbarL[16 * QS];           // 2176 B
  __shared__ __align__(16) unsigned short attnT[32 * 72];  // 4608 B [p][m]
  __shared__ float boutL[256];

  const int tid = threadIdx.x;
  const int lane = tid & 63;
  const int wid = __builtin_amdgcn_readfirstlane(tid >> 6);
  const int col = lane & 15, quad = lane >> 4;
  const int P0 = blockIdx.x * 32;
  const int b = P0 >> 12, s0 = P0 & 4095;

  // ---- stage xp[p][c] (bf16), 32 pixels ----
  for (int i = tid; i < 32 * KP; i += 1024) {
    int c = i >> 5, p = i & 31;
    float vv;
    if (c < 256)        vv = x[(b * 256 + c) * 4096 + s0 + p];
    else if (c < 258)   vv = pos[(c - 256) * 4096 + s0 + p];
    else if (c == 258)  vv = 1.0f;   // bias channel
    else                vv = 0.0f;
    xp[p * KP + c] = f2bf(vv);
  }
  if (tid < 256) boutL[tid] = bout[tid];
  for (int i = tid; i < 16 * QS; i += 1024) qbarL[i] = 0.f;
  __syncthreads();

  // ================= q phase =================
  f32x4 acc[4][2];
#pragma unroll
  for (int ot = 0; ot < 4; ++ot)
#pragma unroll
    for (int nt = 0; nt < 2; ++nt) acc[ot][nt] = (f32x4)0.f;

  {
    const unsigned short* wbase = wsp + WQP_OFF + (wid * 64 + col) * 288 + quad * 8;
#pragma unroll 1
    for (int ks = 0; ks < 9; ++ks) {
      const int kb = ks * 32;
      bf16x8 av[4], bv[2];
#pragma unroll
      for (int ot = 0; ot < 4; ++ot)
        av[ot] = *(const bf16x8*)(wbase + ot * 16 * 288 + kb);
#pragma unroll
      for (int nt = 0; nt < 2; ++nt)
        bv[nt] = *(const bf16x8*)(&xp[(nt * 16 + col) * KP + kb + quad * 8]);
#pragma unroll
      for (int ot = 0; ot < 4; ++ot)
#pragma unroll
        for (int nt = 0; nt < 2; ++nt)
          acc[ot][nt] = __builtin_amdgcn_mfma_f32_16x16x32_bf16(av[ot], bv[nt], acc[ot][nt], 0, 0, 0);
    }
  }

  // normalize each m-group per pixel; accumulate qbar partials
  {
    float qsum[2][4];  // [nt][r]
#pragma unroll
    for (int nt = 0; nt < 2; ++nt)
#pragma unroll
      for (int r = 0; r < 4; ++r) qsum[nt][r] = 0.f;
#pragma unroll
    for (int ot = 0; ot < 4; ++ot) {
#pragma unroll
      for (int nt = 0; nt < 2; ++nt) {
        f32x4 a = acc[ot][nt];
        float s = a[0]*a[0] + a[1]*a[1] + a[2]*a[2] + a[3]*a[3];
        s += __shfl_xor(s, 16, 64);
        s += __shfl_xor(s, 32, 64);
        float inv = 1.0f / fmaxf(sqrtf(s), EPSN);
#pragma unroll
        for (int r = 0; r < 4; ++r) qsum[nt][r] = fmaf(a[r], inv, qsum[nt][r]);
      }
    }
#pragma unroll
    for (int nt = 0; nt < 2; ++nt)
#pragma unroll
      for (int r = 0; r < 4; ++r)
        atomicAdd(&qbarL[(quad * 4 + r) * QS + nt * 16 + col], qsum[nt][r] * (1.0f / 64.0f));
  }
  __syncthreads();

  // ================= k phase =================
#pragma unroll
  for (int ot = 0; ot < 4; ++ot)
#pragma unroll
    for (int nt = 0; nt < 2; ++nt) acc[ot][nt] = (f32x4)0.f;

  {
    const unsigned short* wbase = wsp + WKP_OFF + (wid * 64 + col) * 288 + quad * 8;
#pragma unroll 1
    for (int ks = 0; ks < 9; ++ks) {
      const int kb = ks * 32;
      bf16x8 av[4], bv[2];
#pragma unroll
      for (int ot = 0; ot < 4; ++ot)
        av[ot] = *(const bf16x8*)(wbase + ot * 16 * 288 + kb);
#pragma unroll
      for (int nt = 0; nt < 2; ++nt)
        bv[nt] = *(const bf16x8*)(&xp[(nt * 16 + col) * KP + kb + quad * 8]);
#pragma unroll
      for (int ot = 0; ot < 4; ++ot)
#pragma unroll
        for (int nt = 0; nt < 2; ++nt)
          acc[ot][nt] = __builtin_amdgcn_mfma_f32_16x16x32_bf16(av[ot], bv[nt], acc[ot][nt], 0, 0, 0);
    }
  }

  {
    float qb[2][4];  // [nt][r]
#pragma unroll
    for (int nt = 0; nt < 2; ++nt)
#pragma unroll
      for (int r = 0; r < 4; ++r)
        qb[nt][r] = qbarL[(quad * 4 + r) * QS + nt * 16 + col];

#pragma unroll
    for (int ot = 0; ot < 4; ++ot) {
      const int m = wid * 4 + ot;
#pragma unroll
      for (int nt = 0; nt < 2; ++nt) {
        f32x4 a = acc[ot][nt];
        float s2 = a[0]*a[0] + a[1]*a[1] + a[2]*a[2] + a[3]*a[3];
        float sp = qb[nt][0]*a[0] + qb[nt][1]*a[1] + qb[nt][2]*a[2] + qb[nt][3]*a[3];
        s2 += __shfl_xor(s2, 16, 64);
        s2 += __shfl_xor(s2, 32, 64);
        sp += __shfl_xor(sp, 16, 64);
        sp += __shfl_xor(sp, 32, 64);
        float attn = sp / fmaxf(sqrtf(s2), EPSN);
        if (quad == 0) attnT[(nt * 16 + col) * 72 + m] = f2bf(attn);
      }
    }
  }
  __syncthreads();

  // ================= epilogue: out = x + bout + WVt @ attn =================
  {
    f32x4 e[2];
#pragma unroll
    for (int nt = 0; nt < 2; ++nt) e[nt] = (f32x4)0.f;
    const unsigned short* wvb = wsp + WVP_OFF + (wid * 16 + col) * 64 + quad * 8;
#pragma unroll
    for (int ks = 0; ks < 2; ++ks) {
      bf16x8 av = *(const bf16x8*)(wvb + ks * 32);
#pragma unroll
      for (int nt = 0; nt < 2; ++nt) {
        bf16x8 bv = *(const bf16x8*)(&attnT[(nt * 16 + col) * 72 + ks * 32 + quad * 8]);
        e[nt] = __builtin_amdgcn_mfma_f32_16x16x32_bf16(av, bv, e[nt], 0, 0, 0);
      }
    }
#pragma unroll
    for (int nt = 0; nt < 2; ++nt) {
#pragma unroll
      for (int r = 0; r < 4; ++r) {
        const int o = wid * 16 + quad * 4 + r;
        const int p = nt * 16 + col;
        const int gi = (b * 256 + o) * 4096 + s0 + p;
        out[gi] = x[gi] + boutL[o] + e[nt][r];
      }
    }
  }
}

// =====================================================================
extern "C" void kernel_launch(void* const* d_in, const int* in_sizes, int n_in,
                              void* d_out, int out_size, void* d_ws, size_t ws_size,
                              hipStream_t stream) {
  const float* x    = (const float*)d_in[0];
  const float* pos  = (const float*)d_in[1];
  const float* wq   = (const float*)d_in[2];
  const float* bq   = (const float*)d_in[3];
  const float* wk   = (const float*)d_in[4];
  const float* bk   = (const float*)d_in[5];
  const float* v    = (const float*)d_in[6];
  const float* wout = (const float*)d_in[7];
  const float* bout = (const float*)d_in[8];
  float* out = (float*)d_out;
  unsigned short* wsp = (unsigned short*)d_ws;

  hipLaunchKernelGGL(prep_kernel, dim3(1408), dim3(256), 0, stream,
                     wq, bq, wk, bk, v, wout, wsp);
  hipLaunchKernelGGL(fused_kernel, dim3(512), dim3(1024), 0, stream,
                     x, pos, wsp, bout, out);
}

// Round 6
// 140.350 us; speedup vs baseline: 1.1758x; 1.1758x over previous
//
#include <hip/hip_runtime.h>
#include <stdint.h>

#define EPSN 1e-12f

typedef float f32x4 __attribute__((ext_vector_type(4)));
typedef __bf16 bf16x8 __attribute__((ext_vector_type(8)));
typedef uint32_t u32x4 __attribute__((ext_vector_type(4)));

// ---- bf16 helpers (round-to-nearest-even) ----
__device__ __forceinline__ unsigned short f2bf(float f) {
  union { float f; unsigned int u; } v; v.f = f;
  unsigned int u = v.u + 0x7FFFu + ((v.u >> 16) & 1u);
  return (unsigned short)(u >> 16);
}

// ---- workspace layout (ushort offsets) ----
// Fragment-major packed weights: element (g, ks, lane, j) holds
//   W[o = g*16 + (lane&15)][k = ks*32 + (lane>>4)*8 + j]   (k=258 -> bias, >258 -> 0)
// so a wave's A-load is base + lane*16B : fully coalesced 1KB.
// WQF: [64][9][64][8] = 294912 shorts ; WKF same ; WVP: [256 o][64 m]
#define WQF_OFF 0
#define WKF_OFF (64 * 9 * 64 * 8)
#define WVP_OFF (2 * 64 * 9 * 64 * 8)

// =====================================================================
// prep: fragment-major bf16 weight pack (bias folded) + WVt = wout @ v^T
// blocks [0,144): pack q/k.  blocks [144,400): WVt via quad-split reduce.
// =====================================================================
__global__ __launch_bounds__(256) void prep_kernel(
    const float* __restrict__ wq, const float* __restrict__ bq,
    const float* __restrict__ wk, const float* __restrict__ bk,
    const float* __restrict__ v, const float* __restrict__ wout,
    unsigned short* __restrict__ wsp) {
  if (blockIdx.x < 144) {
    int t = blockIdx.x * 256 + threadIdx.x;  // [0, 36864)
    int lane = t & 63;
    int rest = t >> 6;            // [0, 576)
    int ks = rest % 9, g = rest / 9;
    int col = lane & 15, quad = lane >> 4;
    int o = g * 16 + col;
    int kb = ks * 32 + quad * 8;
    unsigned short q8[8], k8[8];
#pragma unroll
    for (int j = 0; j < 8; ++j) {
      int k = kb + j;
      float vq, vk;
      if (k < 258)       { vq = wq[o * 258 + k]; vk = wk[o * 258 + k]; }
      else if (k == 258) { vq = bq[o];           vk = bk[o]; }
      else               { vq = 0.f;             vk = 0.f; }
      q8[j] = f2bf(vq); k8[j] = f2bf(vk);
    }
    *(u32x4*)(wsp + WQF_OFF + t * 8) = *(u32x4*)q8;
    *(u32x4*)(wsp + WKF_OFF + t * 8) = *(u32x4*)k8;
  } else {
    int idx2 = (blockIdx.x - 144) * 256 + threadIdx.x;  // [0, 65536)
    int fc = idx2 & 3, m = (idx2 >> 2) & 63, o = idx2 >> 8;
    const f32x4* wo = (const f32x4*)(wout + o * 256 + fc * 64);
    const f32x4* vm = (const f32x4*)(v + m * 256 + fc * 64);
    float s = 0.f;
#pragma unroll
    for (int f = 0; f < 16; ++f) {
      f32x4 a = wo[f], bvv = vm[f];
      s += a[0]*bvv[0] + a[1]*bvv[1] + a[2]*bvv[2] + a[3]*bvv[3];
    }
    s += __shfl_xor(s, 1, 64);
    s += __shfl_xor(s, 2, 64);
    if (fc == 0) wsp[WVP_OFF + o * 64 + m] = f2bf(s);
  }
}

// =====================================================================
// fused: stage xp -> q MFMA -> norm/qbar -> k MFMA -> attn -> epilogue
// 64 px/block, 256 blocks; 16 waves; wave w: o-range [w*64, w*64+64)
// =====================================================================
#define KP 296   // xp row stride in bf16 (148 dwords; rows 16B-aligned)
// BUGFIX R5: QS must exceed the 64-pixel index range (R4 leftover 34
// aliased qbar rows: 15*34+63 = 573 > 544). 66 = 64 + 2-pad, as in R3.
#define QS 66    // qbar row stride (floats)

__global__ __launch_bounds__(1024) void fused_kernel(
    const float* __restrict__ x, const float* __restrict__ pos,
    const unsigned short* __restrict__ wsp, const float* __restrict__ bout,
    float* __restrict__ out) {
  __shared__ __align__(16) unsigned short xp[64 * KP];     // 37888 B
  __shared__ __align__(16) float qbarL[16 * QS];           // 4224 B
  __shared__ __align__(16) unsigned short attnT[64 * 72];  // 9216 B [p][m]
  __shared__ float boutL[256];

  const int tid = threadIdx.x;
  const int lane = tid & 63;
  const int wid = __builtin_amdgcn_readfirstlane(tid >> 6);
  const int col = lane & 15, quad = lane >> 4;
  const int P0 = blockIdx.x * 64;
  const int b = P0 >> 12, s0 = P0 & 4095;

  // ---- stage xp[p][c] as packed b32 writes.
  // Lane mapping (dc = i&7, pp = (i>>3)&63, dh = i>>9) gives each wave
  // an 8px x 8dcol tile: LDS write banks = (pp*20 + dc) mod 32 -> 2-way max
  // (free), vs 8-way for the naive p-major mapping (stride 148 % 32 = 20).
  uint32_t* xp32 = (uint32_t*)xp;
  for (int i = tid; i < 64 * 152; i += 1024) {
    int dc = i & 7, pp = (i >> 3) & 63, dh = i >> 9;
    int dcol = dh * 8 + dc;
    if (dcol < 148) {
      int c0 = dcol * 2;
      float v0, v1;
      if (c0 < 256) {
        v0 = x[(b * 256 + c0) * 4096 + s0 + pp];
        v1 = x[(b * 256 + c0 + 1) * 4096 + s0 + pp];
      } else if (c0 == 256) {
        v0 = pos[s0 + pp];
        v1 = pos[4096 + s0 + pp];
      } else {
        v0 = (c0 == 258) ? 1.0f : 0.0f;   // bias channel at 258
        v1 = 0.0f;
      }
      xp32[pp * 148 + dcol] =
          (uint32_t)f2bf(v0) | ((uint32_t)f2bf(v1) << 16);
    }
  }
  if (tid < 256) boutL[tid] = bout[tid];
  for (int i = tid; i < 16 * QS; i += 1024) qbarL[i] = 0.f;
  __syncthreads();

  const unsigned short* aqbase = wsp + WQF_OFF + (wid * 4 * 9 * 64 + lane) * 8;
  const unsigned short* akbase = wsp + WKF_OFF + (wid * 4 * 9 * 64 + lane) * 8;

  // ================= q phase =================
  f32x4 acc[4][4];
#pragma unroll
  for (int ot = 0; ot < 4; ++ot)
#pragma unroll
    for (int nt = 0; nt < 4; ++nt) acc[ot][nt] = (f32x4)0.f;

  {
#pragma unroll
    for (int ks = 0; ks < 9; ++ks) {
      const int kb = ks * 32;
      bf16x8 av[4], bv[4];
#pragma unroll
      for (int ot = 0; ot < 4; ++ot)
        av[ot] = *(const bf16x8*)(aqbase + (ot * 9 + ks) * 512);
#pragma unroll
      for (int nt = 0; nt < 4; ++nt)
        bv[nt] = *(const bf16x8*)(&xp[(nt * 16 + col) * KP + kb + quad * 8]);
#pragma unroll
      for (int ot = 0; ot < 4; ++ot)
#pragma unroll
        for (int nt = 0; nt < 4; ++nt)
          acc[ot][nt] = __builtin_amdgcn_mfma_f32_16x16x32_bf16(av[ot], bv[nt], acc[ot][nt], 0, 0, 0);
    }
  }

  // normalize each m-group per pixel; accumulate qbar partials
  {
    float qsum[4][4];  // [nt][r]
#pragma unroll
    for (int nt = 0; nt < 4; ++nt)
#pragma unroll
      for (int r = 0; r < 4; ++r) qsum[nt][r] = 0.f;
#pragma unroll
    for (int ot = 0; ot < 4; ++ot) {
#pragma unroll
      for (int nt = 0; nt < 4; ++nt) {
        f32x4 a = acc[ot][nt];
        float s = a[0]*a[0] + a[1]*a[1] + a[2]*a[2] + a[3]*a[3];
        s += __shfl_xor(s, 16, 64);
        s += __shfl_xor(s, 32, 64);
        float inv = 1.0f / fmaxf(sqrtf(s), EPSN);
#pragma unroll
        for (int r = 0; r < 4; ++r) qsum[nt][r] = fmaf(a[r], inv, qsum[nt][r]);
      }
    }
#pragma unroll
    for (int nt = 0; nt < 4; ++nt)
#pragma unroll
      for (int r = 0; r < 4; ++r)
        atomicAdd(&qbarL[(quad * 4 + r) * QS + nt * 16 + col], qsum[nt][r] * (1.0f / 64.0f));
  }
  __syncthreads();

  // ================= k phase =================
#pragma unroll
  for (int ot = 0; ot < 4; ++ot)
#pragma unroll
    for (int nt = 0; nt < 4; ++nt) acc[ot][nt] = (f32x4)0.f;

  {
#pragma unroll
    for (int ks = 0; ks < 9; ++ks) {
      const int kb = ks * 32;
      bf16x8 av[4], bv[4];
#pragma unroll
      for (int ot = 0; ot < 4; ++ot)
        av[ot] = *(const bf16x8*)(akbase + (ot * 9 + ks) * 512);
#pragma unroll
      for (int nt = 0; nt < 4; ++nt)
        bv[nt] = *(const bf16x8*)(&xp[(nt * 16 + col) * KP + kb + quad * 8]);
#pragma unroll
      for (int ot = 0; ot < 4; ++ot)
#pragma unroll
        for (int nt = 0; nt < 4; ++nt)
          acc[ot][nt] = __builtin_amdgcn_mfma_f32_16x16x32_bf16(av[ot], bv[nt], acc[ot][nt], 0, 0, 0);
    }
  }

  {
    float qb[4][4];  // [nt][r]
#pragma unroll
    for (int nt = 0; nt < 4; ++nt)
#pragma unroll
      for (int r = 0; r < 4; ++r)
        qb[nt][r] = qbarL[(quad * 4 + r) * QS + nt * 16 + col];

#pragma unroll
    for (int ot = 0; ot < 4; ++ot) {
      const int m = wid * 4 + ot;
#pragma unroll
      for (int nt = 0; nt < 4; ++nt) {
        f32x4 a = acc[ot][nt];
        float s2 = a[0]*a[0] + a[1]*a[1] + a[2]*a[2] + a[3]*a[3];
        float sp = qb[nt][0]*a[0] + qb[nt][1]*a[1] + qb[nt][2]*a[2] + qb[nt][3]*a[3];
        s2 += __shfl_xor(s2, 16, 64);
        s2 += __shfl_xor(s2, 32, 64);
        sp += __shfl_xor(sp, 16, 64);
        sp += __shfl_xor(sp, 32, 64);
        float attn = sp / fmaxf(sqrtf(s2), EPSN);
        if (quad == 0) attnT[(nt * 16 + col) * 72 + m] = f2bf(attn);
      }
    }
  }
  __syncthreads();

  // ================= epilogue: out = x + bout + WVt @ attn =================
  {
    f32x4 e[4];
#pragma unroll
    for (int nt = 0; nt < 4; ++nt) e[nt] = (f32x4)0.f;
    const unsigned short* wvb = wsp + WVP_OFF + (wid * 16 + col) * 64 + quad * 8;
#pragma unroll
    for (int ks = 0; ks < 2; ++ks) {
      bf16x8 av = *(const bf16x8*)(wvb + ks * 32);
#pragma unroll
      for (int nt = 0; nt < 4; ++nt) {
        bf16x8 bv = *(const bf16x8*)(&attnT[(nt * 16 + col) * 72 + ks * 32 + quad * 8]);
        e[nt] = __builtin_amdgcn_mfma_f32_16x16x32_bf16(av, bv, e[nt], 0, 0, 0);
      }
    }
#pragma unroll
    for (int nt = 0; nt < 4; ++nt) {
#pragma unroll
      for (int r = 0; r < 4; ++r) {
        const int o = wid * 16 + quad * 4 + r;
        const int p = nt * 16 + col;
        const int gi = (b * 256 + o) * 4096 + s0 + p;
        out[gi] = x[gi] + boutL[o] + e[nt][r];
      }
    }
  }
}

// =====================================================================
extern "C" void kernel_launch(void* const* d_in, const int* in_sizes, int n_in,
                              void* d_out, int out_size, void* d_ws, size_t ws_size,
                              hipStream_t stream) {
  const float* x    = (const float*)d_in[0];
  const float* pos  = (const float*)d_in[1];
  const float* wq   = (const float*)d_in[2];
  const float* bq   = (const float*)d_in[3];
  const float* wk   = (const float*)d_in[4];
  const float* bk   = (const float*)d_in[5];
  const float* v    = (const float*)d_in[6];
  const float* wout = (const float*)d_in[7];
  const float* bout = (const float*)d_in[8];
  float* out = (float*)d_out;
  unsigned short* wsp = (unsigned short*)d_ws;

  hipLaunchKernelGGL(prep_kernel, dim3(400), dim3(256), 0, stream,
                     wq, bq, wk, bk, v, wout, wsp);
  hipLaunchKernelGGL(fused_kernel, dim3(256), dim3(1024), 0, stream,
                     x, pos, wsp, bout, out);
}

// Round 8
// 136.366 us; speedup vs baseline: 1.2101x; 1.0292x over previous
//
#include <hip/hip_runtime.h>
#include <stdint.h>

#define EPSN 1e-12f

typedef float f32x16 __attribute__((ext_vector_type(16)));
typedef float f32x4 __attribute__((ext_vector_type(4)));
typedef __bf16 bf16x8 __attribute__((ext_vector_type(8)));
typedef uint32_t u32x4 __attribute__((ext_vector_type(4)));

// ---- bf16 helpers (round-to-nearest-even) ----
__device__ __forceinline__ unsigned short f2bf(float f) {
  union { float f; unsigned int u; } v; v.f = f;
  unsigned int u = v.u + 0x7FFFu + ((v.u >> 16) & 1u);
  return (unsigned short)(u >> 16);
}

// ---- workspace layout (ushort offsets) ----
// Fragment-major packed weights for 32x32x16 MFMA:
//   addr = ((g32*18 + ks)*64 + lane)*8 + j
//   value = W[o = g32*32 + (lane&31)][k = ks*16 + (lane>>5)*8 + j]
//   (k=258 -> bias, k>258 -> 0);  wave A-load = base + lane*16B (coalesced 1KB)
#define WQF_OFF 0
#define WKF_OFF (32 * 18 * 64 * 8)
#define WVP_OFF (2 * 32 * 18 * 64 * 8)

// =====================================================================
// prep: fragment-major bf16 weight pack (bias folded) + WVt = wout @ v^T
// =====================================================================
__global__ __launch_bounds__(256) void prep_kernel(
    const float* __restrict__ wq, const float* __restrict__ bq,
    const float* __restrict__ wk, const float* __restrict__ bk,
    const float* __restrict__ v, const float* __restrict__ wout,
    unsigned short* __restrict__ wsp) {
  if (blockIdx.x < 144) {
    int t = blockIdx.x * 256 + threadIdx.x;  // [0, 36864)
    int lane = t & 63;
    int rest = t >> 6;            // [0, 576)
    int ks = rest % 18, g = rest / 18;       // g in [0,32)
    int o = g * 32 + (lane & 31);
    int kb = ks * 16 + (lane >> 5) * 8;
    unsigned short q8[8], k8[8];
#pragma unroll
    for (int j = 0; j < 8; ++j) {
      int k = kb + j;
      float vq, vk;
      if (k < 258)       { vq = wq[o * 258 + k]; vk = wk[o * 258 + k]; }
      else if (k == 258) { vq = bq[o];           vk = bk[o]; }
      else               { vq = 0.f;             vk = 0.f; }
      q8[j] = f2bf(vq); k8[j] = f2bf(vk);
    }
    *(u32x4*)(wsp + WQF_OFF + t * 8) = *(u32x4*)q8;
    *(u32x4*)(wsp + WKF_OFF + t * 8) = *(u32x4*)k8;
  } else {
    int idx2 = (blockIdx.x - 144) * 256 + threadIdx.x;  // [0, 65536)
    int fc = idx2 & 3, m = (idx2 >> 2) & 63, o = idx2 >> 8;
    const f32x4* wo = (const f32x4*)(wout + o * 256 + fc * 64);
    const f32x4* vm = (const f32x4*)(v + m * 256 + fc * 64);
    float s = 0.f;
#pragma unroll
    for (int f = 0; f < 16; ++f) {
      f32x4 a = wo[f], bvv = vm[f];
      s += a[0]*bvv[0] + a[1]*bvv[1] + a[2]*bvv[2] + a[3]*bvv[3];
    }
    s += __shfl_xor(s, 1, 64);
    s += __shfl_xor(s, 2, 64);
    if (fc == 0) wsp[WVP_OFF + o * 64 + m] = f2bf(s);
  }
}

// =====================================================================
// fused: 32 px/block, 512 blocks -> target 2 blocks/CU (regs <= 64/wave).
// 16 waves; projection: wave w covers q/k rows [w*64, w*64+64) as 2 tiles
// of 32x32x16. Epilogue (256 rows only): waves 0..7, one 32x32 tile each.
// C/D layout (verified): col = lane&31 (px), row = (r&3)+8*(r>>2)+4*(lane>>5).
// =====================================================================
#define KP 296   // xp row stride in shorts (148 dwords; rows 16B-aligned)
#define QSS 33   // qbar row stride (floats)
#define AT 72    // attnM row stride (shorts; 144B = 16B-aligned rows)

__global__ __launch_bounds__(1024, 8) void fused_kernel(
    const float* __restrict__ x, const float* __restrict__ pos,
    const unsigned short* __restrict__ wsp, const float* __restrict__ bout,
    float* __restrict__ out) {
  __shared__ __align__(16) unsigned short xp[32 * KP];    // 18944 B
  __shared__ __align__(16) float qbarL[16 * QSS];         // 2112 B  [j][px]
  __shared__ __align__(16) unsigned short attnM[32 * AT]; // 4608 B  [px][m]
  __shared__ float boutL[256];                            // 1024 B

  const int tid = threadIdx.x;
  const int lane = tid & 63;
  const int wid = __builtin_amdgcn_readfirstlane(tid >> 6);
  const int px = lane & 31, q2 = lane >> 5;
  const int P0 = blockIdx.x * 32;
  const int b = P0 >> 12, s0 = P0 & 4095;

  // ---- stage xp[p][c] as packed b32 writes (2-way banks max) ----
  uint32_t* xp32 = (uint32_t*)xp;
  for (int i = tid; i < 32 * 152; i += 1024) {
    int dc = i & 7, pp = (i >> 3) & 31, dh = i >> 8;
    int dcol = dh * 8 + dc;
    if (dcol < 148) {
      int c0 = dcol * 2;
      float v0, v1;
      if (c0 < 256) {
        v0 = x[(b * 256 + c0) * 4096 + s0 + pp];
        v1 = x[(b * 256 + c0 + 1) * 4096 + s0 + pp];
      } else if (c0 == 256) {
        v0 = pos[s0 + pp];
        v1 = pos[4096 + s0 + pp];
      } else {
        v0 = (c0 == 258) ? 1.0f : 0.0f;   // bias channel at 258
        v1 = 0.0f;
      }
      xp32[pp * 148 + dcol] =
          (uint32_t)f2bf(v0) | ((uint32_t)f2bf(v1) << 16);
    }
  }
  if (tid < 256) boutL[tid] = bout[tid];
  if (tid < 16 * QSS) qbarL[tid] = 0.f;
  __syncthreads();

  // BUGFIX R7: tile stride is 18*64*8 = 9216 elements; wid term needs the *8
  // (was wid*2*18*64 -> every wave read the wrong (mostly wave-0) fragments).
  const unsigned short* aqb = wsp + WQF_OFF + wid * 2 * 9216 + lane * 8;
  const unsigned short* akb = wsp + WKF_OFF + wid * 2 * 9216 + lane * 8;
  const unsigned short* xb = &xp[px * KP + q2 * 8];

  // ================= q phase =================
  f32x16 acc0 = (f32x16)0.f, acc1 = (f32x16)0.f;
#pragma unroll
  for (int ks = 0; ks < 18; ++ks) {
    bf16x8 a0 = *(const bf16x8*)(aqb + ks * 512);
    bf16x8 a1 = *(const bf16x8*)(aqb + 9216 + ks * 512);
    bf16x8 bv = *(const bf16x8*)(xb + ks * 16);
    acc0 = __builtin_amdgcn_mfma_f32_32x32x16_bf16(a0, bv, acc0, 0, 0, 0);
    acc1 = __builtin_amdgcn_mfma_f32_32x32x16_bf16(a1, bv, acc1, 0, 0, 0);
  }

  // normalize per m (16 j each) and accumulate qbar partials
  {
    float qsum[8];
#pragma unroll
    for (int r = 0; r < 8; ++r) qsum[r] = 0.f;
#pragma unroll
    for (int t = 0; t < 2; ++t) {
      const f32x16 a = t ? acc1 : acc0;
      float s20 = 0.f, s21 = 0.f;
#pragma unroll
      for (int r = 0; r < 8; ++r) { s20 = fmaf(a[r], a[r], s20); s21 = fmaf(a[r + 8], a[r + 8], s21); }
      s20 += __shfl_xor(s20, 32, 64);
      s21 += __shfl_xor(s21, 32, 64);
      float i0 = 1.0f / fmaxf(sqrtf(s20), EPSN);
      float i1 = 1.0f / fmaxf(sqrtf(s21), EPSN);
#pragma unroll
      for (int r = 0; r < 8; ++r) qsum[r] += a[r] * i0 + a[r + 8] * i1;
    }
#pragma unroll
    for (int r = 0; r < 8; ++r) {
      int j = (r & 3) + ((r >> 2) << 3) + (q2 << 2);
      atomicAdd(&qbarL[j * QSS + px], qsum[r] * (1.0f / 64.0f));
    }
  }
  __syncthreads();

  // ================= k phase =================
  acc0 = (f32x16)0.f; acc1 = (f32x16)0.f;
#pragma unroll
  for (int ks = 0; ks < 18; ++ks) {
    bf16x8 a0 = *(const bf16x8*)(akb + ks * 512);
    bf16x8 a1 = *(const bf16x8*)(akb + 9216 + ks * 512);
    bf16x8 bv = *(const bf16x8*)(xb + ks * 16);
    acc0 = __builtin_amdgcn_mfma_f32_32x32x16_bf16(a0, bv, acc0, 0, 0, 0);
    acc1 = __builtin_amdgcn_mfma_f32_32x32x16_bf16(a1, bv, acc1, 0, 0, 0);
  }

  {
    float qb[8];
#pragma unroll
    for (int r = 0; r < 8; ++r) {
      int j = (r & 3) + ((r >> 2) << 3) + (q2 << 2);
      qb[r] = qbarL[j * QSS + px];
    }
#pragma unroll
    for (int t = 0; t < 2; ++t) {
      const f32x16 a = t ? acc1 : acc0;
      float s20 = 0.f, s21 = 0.f, sp0 = 0.f, sp1 = 0.f;
#pragma unroll
      for (int r = 0; r < 8; ++r) {
        s20 = fmaf(a[r], a[r], s20);         sp0 = fmaf(qb[r], a[r], sp0);
        s21 = fmaf(a[r + 8], a[r + 8], s21); sp1 = fmaf(qb[r], a[r + 8], sp1);
      }
      s20 += __shfl_xor(s20, 32, 64);
      s21 += __shfl_xor(s21, 32, 64);
      sp0 += __shfl_xor(sp0, 32, 64);
      sp1 += __shfl_xor(sp1, 32, 64);
      if (q2 == 0) {
        int m0 = wid * 4 + t * 2;
        attnM[px * AT + m0]     = f2bf(sp0 / fmaxf(sqrtf(s20), EPSN));
        attnM[px * AT + m0 + 1] = f2bf(sp1 / fmaxf(sqrtf(s21), EPSN));
      }
    }
  }
  __syncthreads();

  // ================= epilogue: out = x + bout + WVt @ attn =================
  // BUGFIX R7: only 256 output rows -> 8 tiles of 32. Waves 0..7 each do one
  // tile (o = wid*32 + row); waves 8..15 idle. (R7 used wid*64 -> OOB write.)
  if (wid < 8) {
    f32x16 e0 = (f32x16)0.f;
    const unsigned short* wv0 = wsp + WVP_OFF + (wid * 32 + px) * 64 + q2 * 8;
    const unsigned short* ab = &attnM[px * AT + q2 * 8];
#pragma unroll
    for (int ks = 0; ks < 4; ++ks) {
      bf16x8 a0 = *(const bf16x8*)(wv0 + ks * 16);
      bf16x8 bv = *(const bf16x8*)(ab + ks * 16);
      e0 = __builtin_amdgcn_mfma_f32_32x32x16_bf16(a0, bv, e0, 0, 0, 0);
    }
#pragma unroll
    for (int r = 0; r < 16; ++r) {
      const int o0 = wid * 32 + (r & 3) + (((r >> 2) & 1) << 3) + (q2 << 2) + ((r >> 3) << 4);
      const int gi0 = (b * 256 + o0) * 4096 + s0 + px;
      out[gi0] = x[gi0] + boutL[o0] + e0[r];
    }
  }
}

// =====================================================================
extern "C" void kernel_launch(void* const* d_in, const int* in_sizes, int n_in,
                              void* d_out, int out_size, void* d_ws, size_t ws_size,
                              hipStream_t stream) {
  const float* x    = (const float*)d_in[0];
  const float* pos  = (const float*)d_in[1];
  const float* wq   = (const float*)d_in[2];
  const float* bq   = (const float*)d_in[3];
  const float* wk   = (const float*)d_in[4];
  const float* bk   = (const float*)d_in[5];
  const float* v    = (const float*)d_in[6];
  const float* wout = (const float*)d_in[7];
  const float* bout = (const float*)d_in[8];
  float* out = (float*)d_out;
  unsigned short* wsp = (unsigned short*)d_ws;

  hipLaunchKernelGGL(prep_kernel, dim3(400), dim3(256), 0, stream,
                     wq, bq, wk, bk, v, wout, wsp);
  hipLaunchKernelGGL(fused_kernel, dim3(512), dim3(1024), 0, stream,
                     x, pos, wsp, bout, out);
}

// Round 9
// 136.268 us; speedup vs baseline: 1.2110x; 1.0007x over previous
//
#include <hip/hip_runtime.h>
#include <stdint.h>

#define EPSN 1e-12f

typedef float f32x16 __attribute__((ext_vector_type(16)));
typedef float f32x4 __attribute__((ext_vector_type(4)));
typedef __bf16 bf16x8 __attribute__((ext_vector_type(8)));
typedef uint32_t u32x4 __attribute__((ext_vector_type(4)));

// ---- bf16 helpers (round-to-nearest-even) ----
__device__ __forceinline__ unsigned short f2bf(float f) {
  union { float f; unsigned int u; } v; v.f = f;
  unsigned int u = v.u + 0x7FFFu + ((v.u >> 16) & 1u);
  return (unsigned short)(u >> 16);
}

// async global->LDS DMA, 16B per lane. LDS dest must be wave-uniform;
// HW writes lane i at ldsbase + i*16.
__device__ __forceinline__ void dma16(const void* g, void* l) {
  __builtin_amdgcn_global_load_lds(
      (const __attribute__((address_space(1))) unsigned int*)g,
      (__attribute__((address_space(3))) unsigned int*)l, 16, 0, 0);
}

// ---- workspace layout (ushort offsets) ----
// Fragment-major packed weights for 32x32x16 MFMA:
//   addr = ((tile*18 + ks)*64 + lane)*8 + j
//   value = W[o = tile*32 + (lane&31)][k = ks*16 + (lane>>5)*8 + j]
//   (k=258 -> bias, k>258 -> 0). One (tile,ks) chunk = 1KB, DMA-able.
#define WQF_OFF 0
#define WKF_OFF (32 * 18 * 64 * 8)
#define WVP_OFF (2 * 32 * 18 * 64 * 8)

// =====================================================================
// prep: fragment-major bf16 weight pack (bias folded) + WVt = wout @ v^T
// blocks [0,288): pack (q jobs then k jobs).  blocks [288,544): WVt.
// =====================================================================
__global__ __launch_bounds__(256) void prep_kernel(
    const float* __restrict__ wq, const float* __restrict__ bq,
    const float* __restrict__ wk, const float* __restrict__ bk,
    const float* __restrict__ v, const float* __restrict__ wout,
    unsigned short* __restrict__ wsp) {
  if (blockIdx.x < 288) {
    int t2 = blockIdx.x * 256 + threadIdx.x;   // [0, 73728)
    int isK = t2 >= 36864;
    int t = isK ? t2 - 36864 : t2;
    const float* w = isK ? wk : wq;
    const float* bb = isK ? bk : bq;
    unsigned short* dst = wsp + (isK ? WKF_OFF : WQF_OFF);
    int lane = t & 63, rest = t >> 6;          // rest in [0,576)
    int ks = rest % 18, g = rest / 18;         // g in [0,32)
    int o = g * 32 + (lane & 31);
    int kb = ks * 16 + (lane >> 5) * 8;
    unsigned short v8[8];
#pragma unroll
    for (int j = 0; j < 8; ++j) {
      int k = kb + j;
      float val;
      if (k < 258)       val = w[o * 258 + k];
      else if (k == 258) val = bb[o];
      else               val = 0.f;
      v8[j] = f2bf(val);
    }
    *(u32x4*)(dst + t * 8) = *(u32x4*)v8;
  } else {
    int idx2 = (blockIdx.x - 288) * 256 + threadIdx.x;  // [0, 65536)
    int fc = idx2 & 3, m = (idx2 >> 2) & 63, o = idx2 >> 8;
    const f32x4* wo = (const f32x4*)(wout + o * 256 + fc * 64);
    const f32x4* vm = (const f32x4*)(v + m * 256 + fc * 64);
    float s = 0.f;
#pragma unroll
    for (int f = 0; f < 16; ++f) {
      f32x4 a = wo[f], bvv = vm[f];
      s += a[0]*bvv[0] + a[1]*bvv[1] + a[2]*bvv[2] + a[3]*bvv[3];
    }
    s += __shfl_xor(s, 1, 64);
    s += __shfl_xor(s, 2, 64);
    if (fc == 0) wsp[WVP_OFF + o * 64 + m] = f2bf(s);
  }
}

// =====================================================================
// fused: 64 px/block, 256 blocks, 16 waves, 1 block/CU (147KB LDS).
// A-stream via global_load_lds DMA, 3-slot pipeline, per-wave vmcnt —
// NO barrier in the K-loop (each wave consumes only its own chunks).
// Wave w: o-tiles 2w,2w+1 (rows [w*64,w*64+64)) x 2 px-tiles (64 px).
// C/D (verified): col=lane&31(px), row=(r&3)+8*(r>>2)+4*(lane>>5).
// =====================================================================
#define KP 296   // xp row stride in shorts
#define QS 66    // qbar row stride (floats)
#define AT 72    // attnM row stride (shorts)

__global__ __launch_bounds__(1024, 4) void fused_kernel(
    const float* __restrict__ x, const float* __restrict__ pos,
    const unsigned short* __restrict__ wsp, const float* __restrict__ bout,
    float* __restrict__ out) {
  __shared__ __align__(16) unsigned short aBuf[3 * 32 * 512];  // 98304 B
  __shared__ __align__(16) unsigned short xp[64 * KP];         // 37888 B
  __shared__ __align__(16) float qbarL[16 * QS];               // 4224 B
  __shared__ __align__(16) unsigned short attnM[64 * AT];      // 9216 B
  __shared__ float boutL[256];                                 // 1024 B

  const int tid = threadIdx.x;
  const int lane = tid & 63;
  const int wid = __builtin_amdgcn_readfirstlane(tid >> 6);
  const int px = lane & 31, q2 = lane >> 5;
  const int P0 = blockIdx.x * 64;
  const int b = P0 >> 12, s0 = P0 & 4095;

  // ---- stage xp[p][c] as packed b32 writes (<=2-way banks) ----
  uint32_t* xp32 = (uint32_t*)xp;
  for (int i = tid; i < 64 * 152; i += 1024) {
    int dc = i & 7, pp = (i >> 3) & 63, dh = i >> 9;
    int dcol = dh * 8 + dc;
    if (dcol < 148) {
      int c0 = dcol * 2;
      float v0, v1;
      if (c0 < 256) {
        v0 = x[(b * 256 + c0) * 4096 + s0 + pp];
        v1 = x[(b * 256 + c0 + 1) * 4096 + s0 + pp];
      } else if (c0 == 256) {
        v0 = pos[s0 + pp];
        v1 = pos[4096 + s0 + pp];
      } else {
        v0 = (c0 == 258) ? 1.0f : 0.0f;   // bias channel
        v1 = 0.0f;
      }
      xp32[pp * 148 + dcol] = (uint32_t)f2bf(v0) | ((uint32_t)f2bf(v1) << 16);
    }
  }
  if (tid < 256) boutL[tid] = bout[tid];
  for (int i = tid; i < 16 * QS; i += 1024) qbarL[i] = 0.f;  // 1056 > 1024!
  __syncthreads();

#define ISSUE(wb, ks_) do {                                              \
    int _sl = (ks_) % 3;                                                 \
    dma16(wb + ((2 * wid) * 18 + (ks_)) * 512 + lane * 8,                \
          &aBuf[_sl * 16384 + (2 * wid) * 512]);                         \
    dma16(wb + ((2 * wid + 1) * 18 + (ks_)) * 512 + lane * 8,            \
          &aBuf[_sl * 16384 + (2 * wid + 1) * 512]);                     \
  } while (0)

#define COMPUTE(ks_) do {                                                \
    int _sl = (ks_) % 3;                                                 \
    bf16x8 _a0 = *(const bf16x8*)&aBuf[_sl * 16384 + (2 * wid) * 512 + lane * 8];     \
    bf16x8 _a1 = *(const bf16x8*)&aBuf[_sl * 16384 + (2 * wid + 1) * 512 + lane * 8]; \
    bf16x8 _b0 = *(const bf16x8*)&xp[px * KP + (ks_) * 16 + q2 * 8];     \
    bf16x8 _b1 = *(const bf16x8*)&xp[(32 + px) * KP + (ks_) * 16 + q2 * 8]; \
    acc00 = __builtin_amdgcn_mfma_f32_32x32x16_bf16(_a0, _b0, acc00, 0, 0, 0); \
    acc01 = __builtin_amdgcn_mfma_f32_32x32x16_bf16(_a0, _b1, acc01, 0, 0, 0); \
    acc10 = __builtin_amdgcn_mfma_f32_32x32x16_bf16(_a1, _b0, acc10, 0, 0, 0); \
    acc11 = __builtin_amdgcn_mfma_f32_32x32x16_bf16(_a1, _b1, acc11, 0, 0, 0); \
  } while (0)

// vmcnt discipline (per wave, only DMA ops in flight inside a phase):
// prologue 4 outstanding; each iter issues 2 more then waits to 4 ->
// oldest slice done. Tail peeled to vmcnt(2)/vmcnt(0).
#define PHASE(wb) do {                                                   \
    ISSUE(wb, 0); ISSUE(wb, 1);                                          \
    _Pragma("unroll 4")                                                  \
    for (int ks = 0; ks < 16; ++ks) {                                    \
      asm volatile("" ::: "memory");                                     \
      ISSUE(wb, ks + 2);                                                 \
      asm volatile("s_waitcnt vmcnt(4)" ::: "memory");                   \
      COMPUTE(ks);                                                       \
    }                                                                    \
    asm volatile("s_waitcnt vmcnt(2)" ::: "memory");                     \
    COMPUTE(16);                                                         \
    asm volatile("s_waitcnt vmcnt(0)" ::: "memory");                     \
    COMPUTE(17);                                                         \
  } while (0)

  // ================= q phase =================
  f32x16 acc00 = (f32x16)0.f, acc01 = (f32x16)0.f,
         acc10 = (f32x16)0.f, acc11 = (f32x16)0.f;
  PHASE((wsp + WQF_OFF));

  // normalize per m; accumulate qbar partials
  {
    float qsum[2][8];
#pragma unroll
    for (int nt = 0; nt < 2; ++nt)
#pragma unroll
      for (int r = 0; r < 8; ++r) qsum[nt][r] = 0.f;
#pragma unroll
    for (int ot = 0; ot < 2; ++ot) {
#pragma unroll
      for (int nt = 0; nt < 2; ++nt) {
        const f32x16 a = ot ? (nt ? acc11 : acc10) : (nt ? acc01 : acc00);
        float s20 = 0.f, s21 = 0.f;
#pragma unroll
        for (int r = 0; r < 8; ++r) {
          s20 = fmaf(a[r], a[r], s20);
          s21 = fmaf(a[r + 8], a[r + 8], s21);
        }
        s20 += __shfl_xor(s20, 32, 64);
        s21 += __shfl_xor(s21, 32, 64);
        float i0 = 1.0f / fmaxf(sqrtf(s20), EPSN);
        float i1 = 1.0f / fmaxf(sqrtf(s21), EPSN);
#pragma unroll
        for (int r = 0; r < 8; ++r) qsum[nt][r] += a[r] * i0 + a[r + 8] * i1;
      }
    }
#pragma unroll
    for (int nt = 0; nt < 2; ++nt)
#pragma unroll
      for (int r = 0; r < 8; ++r) {
        int j = (r & 3) + ((r >> 2) << 3) + (q2 << 2);
        atomicAdd(&qbarL[j * QS + nt * 32 + px], qsum[nt][r] * (1.0f / 64.0f));
      }
  }
  __syncthreads();

  // ================= k phase =================
  acc00 = (f32x16)0.f; acc01 = (f32x16)0.f;
  acc10 = (f32x16)0.f; acc11 = (f32x16)0.f;
  PHASE((wsp + WKF_OFF));

  {
    float qb[2][8];
#pragma unroll
    for (int nt = 0; nt < 2; ++nt)
#pragma unroll
      for (int r = 0; r < 8; ++r) {
        int j = (r & 3) + ((r >> 2) << 3) + (q2 << 2);
        qb[nt][r] = qbarL[j * QS + nt * 32 + px];
      }
#pragma unroll
    for (int ot = 0; ot < 2; ++ot) {
#pragma unroll
      for (int nt = 0; nt < 2; ++nt) {
        const f32x16 a = ot ? (nt ? acc11 : acc10) : (nt ? acc01 : acc00);
        float s20 = 0.f, s21 = 0.f, sp0 = 0.f, sp1 = 0.f;
#pragma unroll
        for (int r = 0; r < 8; ++r) {
          s20 = fmaf(a[r], a[r], s20);         sp0 = fmaf(qb[nt][r], a[r], sp0);
          s21 = fmaf(a[r + 8], a[r + 8], s21); sp1 = fmaf(qb[nt][r], a[r + 8], sp1);
        }
        s20 += __shfl_xor(s20, 32, 64);
        s21 += __shfl_xor(s21, 32, 64);
        sp0 += __shfl_xor(sp0, 32, 64);
        sp1 += __shfl_xor(sp1, 32, 64);
        if (q2 == 0) {
          int m0 = wid * 4 + ot * 2;
          attnM[(nt * 32 + px) * AT + m0]     = f2bf(sp0 / fmaxf(sqrtf(s20), EPSN));
          attnM[(nt * 32 + px) * AT + m0 + 1] = f2bf(sp1 / fmaxf(sqrtf(s21), EPSN));
        }
      }
    }
  }
  __syncthreads();

  // ================= epilogue: out = x + bout + WVt @ attn =================
  // 16 tiles (8 o-tiles x 2 px-tiles); one per wave.
  {
    const int otile = wid >> 1, pxt = wid & 1;
    f32x16 e = (f32x16)0.f;
    const unsigned short* wv = wsp + WVP_OFF + (otile * 32 + px) * 64 + q2 * 8;
    const unsigned short* ab = &attnM[(pxt * 32 + px) * AT + q2 * 8];
#pragma unroll
    for (int ks = 0; ks < 4; ++ks) {
      bf16x8 av = *(const bf16x8*)(wv + ks * 16);
      bf16x8 bv = *(const bf16x8*)(ab + ks * 16);
      e = __builtin_amdgcn_mfma_f32_32x32x16_bf16(av, bv, e, 0, 0, 0);
    }
#pragma unroll
    for (int r = 0; r < 16; ++r) {
      const int o = otile * 32 + (r & 3) + ((r >> 2) << 3) + (q2 << 2);
      const int p = pxt * 32 + px;
      const int gi = (b * 256 + o) * 4096 + s0 + p;
      out[gi] = x[gi] + boutL[o] + e[r];
    }
  }
#undef PHASE
#undef COMPUTE
#undef ISSUE
}

// =====================================================================
extern "C" void kernel_launch(void* const* d_in, const int* in_sizes, int n_in,
                              void* d_out, int out_size, void* d_ws, size_t ws_size,
                              hipStream_t stream) {
  const float* x    = (const float*)d_in[0];
  const float* pos  = (const float*)d_in[1];
  const float* wq   = (const float*)d_in[2];
  const float* bq   = (const float*)d_in[3];
  const float* wk   = (const float*)d_in[4];
  const float* bk   = (const float*)d_in[5];
  const float* v    = (const float*)d_in[6];
  const float* wout = (const float*)d_in[7];
  const float* bout = (const float*)d_in[8];
  float* out = (float*)d_out;
  unsigned short* wsp = (unsigned short*)d_ws;

  hipLaunchKernelGGL(prep_kernel, dim3(544), dim3(256), 0, stream,
                     wq, bq, wk, bk, v, wout, wsp);
  hipLaunchKernelGGL(fused_kernel, dim3(256), dim3(1024), 0, stream,
                     x, pos, wsp, bout, out);
}

// Round 10
// 130.869 us; speedup vs baseline: 1.2610x; 1.0413x over previous
//
#include <hip/hip_runtime.h>
#include <stdint.h>

#define EPSN 1e-12f

typedef float f32x16 __attribute__((ext_vector_type(16)));
typedef float f32x4 __attribute__((ext_vector_type(4)));
typedef __bf16 bf16x8 __attribute__((ext_vector_type(8)));

// ---- bf16 helpers (round-to-nearest-even) ----
__device__ __forceinline__ unsigned short f2bf(float f) {
  union { float f; unsigned int u; } v; v.f = f;
  unsigned int u = v.u + 0x7FFFu + ((v.u >> 16) & 1u);
  return (unsigned short)(u >> 16);
}

// async global->LDS DMA, 16B per lane; LDS dest wave-uniform base.
__device__ __forceinline__ void dma16(const void* g, void* l) {
  __builtin_amdgcn_global_load_lds(
      (const __attribute__((address_space(1))) unsigned int*)g,
      (__attribute__((address_space(3))) unsigned int*)l, 16, 0, 0);
}

// ---- workspace layout (ushort offsets) ----
// Fragment-major packed weights for 32x32x16 MFMA:
//   addr = ((tile*18 + ks)*64 + hi*32 + col)*8 + j
//   value = W[o = tile*32 + col][k = ks*16 + hi*8 + j]  (k=258 bias, >258 zero)
#define WQF_OFF 0
#define WKF_OFF (32 * 18 * 64 * 8)
#define WVP_OFF (2 * 32 * 18 * 64 * 8)

// =====================================================================
// prep v2 (R10): fully parallel + coalesced.
// blocks [0,512): pack (4 o-rows each; bid<256 -> wq, else wk).
//   float2 row-reads are coalesced; fragment writes scatter (no stall).
// blocks [512,1536): WVt; 16 lanes per (o,m), 4x float4 + shuffle reduce.
// =====================================================================
__global__ __launch_bounds__(256) void prep_kernel(
    const float* __restrict__ wq, const float* __restrict__ bq,
    const float* __restrict__ wk, const float* __restrict__ bk,
    const float* __restrict__ v, const float* __restrict__ wout,
    unsigned short* __restrict__ wsp) {
  int bid = blockIdx.x;
  if (bid < 512) {
    int isK = bid >= 256;
    int ob = (bid & 255) * 4;
    const float* w = isK ? wk : wq;
    const float* bb = isK ? bk : bq;
    unsigned short* dst = wsp + (isK ? WKF_OFF : WQF_OFF);
    // k 0..257 as 129 float2 per row
    for (int i = threadIdx.x; i < 4 * 129; i += 256) {
      int r = i / 129, q = i - r * 129;
      int o = ob + r, k = q * 2;
      float2 w2 = *(const float2*)(w + o * 258 + k);
      int g = o >> 5, col = o & 31;
      int ks = k >> 4, hi = (k >> 3) & 1, j = k & 7;
      uint32_t pk = (uint32_t)f2bf(w2.x) | ((uint32_t)f2bf(w2.y) << 16);
      *(uint32_t*)(dst + (((g * 18 + ks) * 64 + hi * 32 + col) << 3) + j) = pk;
    }
    // k 258 (bias) and 259..287 (zero)
    for (int i = threadIdx.x; i < 4 * 30; i += 256) {
      int r = i / 30, kk = 258 + (i - r * 30);
      int o = ob + r;
      int g = o >> 5, col = o & 31;
      int ks = kk >> 4, hi = (kk >> 3) & 1, j = kk & 7;
      dst[(((g * 18 + ks) * 64 + hi * 32 + col) << 3) + j] =
          (kk == 258) ? f2bf(bb[o]) : (unsigned short)0;
    }
  } else {
    int idx = (bid - 512) * 256 + threadIdx.x;  // [0, 262144)
    int fc = idx & 15, m = (idx >> 4) & 63, o = idx >> 10;
    const f32x4* wo = (const f32x4*)(wout + o * 256 + fc * 16);
    const f32x4* vm = (const f32x4*)(v + m * 256 + fc * 16);
    float s = 0.f;
#pragma unroll
    for (int f = 0; f < 4; ++f) {
      f32x4 a = wo[f], bvv = vm[f];
      s += a[0]*bvv[0] + a[1]*bvv[1] + a[2]*bvv[2] + a[3]*bvv[3];
    }
    s += __shfl_xor(s, 1, 64);
    s += __shfl_xor(s, 2, 64);
    s += __shfl_xor(s, 4, 64);
    s += __shfl_xor(s, 8, 64);
    if (fc == 0) wsp[WVP_OFF + o * 64 + m] = f2bf(s);
  }
}

// =====================================================================
// fused: 64 px/block, 256 blocks, 16 waves, 1 block/CU (150KB LDS).
// A-stream via global_load_lds DMA, 3-slot ring, per-wave vmcnt, no
// K-loop barrier. R10: DMA warm-up overlapped with staging (q) and with
// the norm section (k); B ds_reads hoisted above the vmcnt wait.
// =====================================================================
#define KP 296   // xp row stride in shorts
#define QS 66    // qbar row stride (floats)
#define AT 72    // attnM row stride (shorts)

__global__ __launch_bounds__(1024, 4) void fused_kernel(
    const float* __restrict__ x, const float* __restrict__ pos,
    const unsigned short* __restrict__ wsp, const float* __restrict__ bout,
    float* __restrict__ out) {
  __shared__ __align__(16) unsigned short aBuf[3 * 32 * 512];  // 98304 B
  __shared__ __align__(16) unsigned short xp[64 * KP];         // 37888 B
  __shared__ __align__(16) float qbarL[16 * QS];               // 4224 B
  __shared__ __align__(16) unsigned short attnM[64 * AT];      // 9216 B
  __shared__ float boutL[256];                                 // 1024 B

  const int tid = threadIdx.x;
  const int lane = tid & 63;
  const int wid = __builtin_amdgcn_readfirstlane(tid >> 6);
  const int px = lane & 31, q2 = lane >> 5;
  const int P0 = blockIdx.x * 64;
  const int b = P0 >> 12, s0 = P0 & 4095;

#define ISSUE(wb, ks_) do {                                              \
    int _sl = (ks_) % 3;                                                 \
    dma16(wb + ((2 * wid) * 18 + (ks_)) * 512 + lane * 8,                \
          &aBuf[_sl * 16384 + (2 * wid) * 512]);                         \
    dma16(wb + ((2 * wid + 1) * 18 + (ks_)) * 512 + lane * 8,            \
          &aBuf[_sl * 16384 + (2 * wid + 1) * 512]);                     \
  } while (0)

  // q-phase DMA warm-up: latency hidden behind the staging phase.
  ISSUE((wsp + WQF_OFF), 0);
  ISSUE((wsp + WQF_OFF), 1);

  // ---- stage xp[p][c] as packed b32 writes ----
  uint32_t* xp32 = (uint32_t*)xp;
  for (int i = tid; i < 64 * 152; i += 1024) {
    int dc = i & 7, pp = (i >> 3) & 63, dh = i >> 9;
    int dcol = dh * 8 + dc;
    if (dcol < 148) {
      int c0 = dcol * 2;
      float v0, v1;
      if (c0 < 256) {
        v0 = x[(b * 256 + c0) * 4096 + s0 + pp];
        v1 = x[(b * 256 + c0 + 1) * 4096 + s0 + pp];
      } else if (c0 == 256) {
        v0 = pos[s0 + pp];
        v1 = pos[4096 + s0 + pp];
      } else {
        v0 = (c0 == 258) ? 1.0f : 0.0f;
        v1 = 0.0f;
      }
      xp32[pp * 148 + dcol] = (uint32_t)f2bf(v0) | ((uint32_t)f2bf(v1) << 16);
    }
  }
  if (tid < 256) boutL[tid] = bout[tid];
  for (int i = tid; i < 16 * QS; i += 1024) qbarL[i] = 0.f;
  __syncthreads();

#define COMPUTEA(ks_, b0_, b1_) do {                                     \
    int _sl = (ks_) % 3;                                                 \
    bf16x8 _a0 = *(const bf16x8*)&aBuf[_sl * 16384 + (2 * wid) * 512 + lane * 8];     \
    bf16x8 _a1 = *(const bf16x8*)&aBuf[_sl * 16384 + (2 * wid + 1) * 512 + lane * 8]; \
    acc00 = __builtin_amdgcn_mfma_f32_32x32x16_bf16(_a0, b0_, acc00, 0, 0, 0); \
    acc01 = __builtin_amdgcn_mfma_f32_32x32x16_bf16(_a0, b1_, acc01, 0, 0, 0); \
    acc10 = __builtin_amdgcn_mfma_f32_32x32x16_bf16(_a1, b0_, acc10, 0, 0, 0); \
    acc11 = __builtin_amdgcn_mfma_f32_32x32x16_bf16(_a1, b1_, acc11, 0, 0, 0); \
  } while (0)

// Per iter: hoist B ds_reads (independent of DMA) above the vmcnt wait,
// then issue slice ks+2, wait slice ks ready, read A, MFMA.
// vmcnt algebra (slices 0,1 drained by the staging/norm barrier):
// iter0: +2 -> 2, wait(4) nop; iter1: 4, nop; iter2+: 6 -> wait(4) = slice
// ks ready. Tail vmcnt(2)/(0) as before. Correct with or without drain.
#define PHASE(wb) do {                                                   \
    _Pragma("unroll 4")                                                  \
    for (int ks = 0; ks < 16; ++ks) {                                    \
      bf16x8 _b0 = *(const bf16x8*)&xp[px * KP + ks * 16 + q2 * 8];      \
      bf16x8 _b1 = *(const bf16x8*)&xp[(32 + px) * KP + ks * 16 + q2 * 8]; \
      ISSUE(wb, ks + 2);                                                 \
      asm volatile("s_waitcnt vmcnt(4)" ::: "memory");                   \
      COMPUTEA(ks, _b0, _b1);                                            \
    }                                                                    \
    {                                                                    \
      bf16x8 _b0 = *(const bf16x8*)&xp[px * KP + 16 * 16 + q2 * 8];      \
      bf16x8 _b1 = *(const bf16x8*)&xp[(32 + px) * KP + 16 * 16 + q2 * 8]; \
      asm volatile("s_waitcnt vmcnt(2)" ::: "memory");                   \
      COMPUTEA(16, _b0, _b1);                                            \
    }                                                                    \
    {                                                                    \
      bf16x8 _b0 = *(const bf16x8*)&xp[px * KP + 17 * 16 + q2 * 8];      \
      bf16x8 _b1 = *(const bf16x8*)&xp[(32 + px) * KP + 17 * 16 + q2 * 8]; \
      asm volatile("s_waitcnt vmcnt(0)" ::: "memory");                   \
      COMPUTEA(17, _b0, _b1);                                            \
    }                                                                    \
  } while (0)

  // ================= q phase =================
  f32x16 acc00 = (f32x16)0.f, acc01 = (f32x16)0.f,
         acc10 = (f32x16)0.f, acc11 = (f32x16)0.f;
  PHASE((wsp + WQF_OFF));

  // k-phase DMA warm-up: latency hidden behind the norm section.
  ISSUE((wsp + WKF_OFF), 0);
  ISSUE((wsp + WKF_OFF), 1);

  // normalize per m; accumulate qbar partials
  {
    float qsum[2][8];
#pragma unroll
    for (int nt = 0; nt < 2; ++nt)
#pragma unroll
      for (int r = 0; r < 8; ++r) qsum[nt][r] = 0.f;
#pragma unroll
    for (int ot = 0; ot < 2; ++ot) {
#pragma unroll
      for (int nt = 0; nt < 2; ++nt) {
        const f32x16 a = ot ? (nt ? acc11 : acc10) : (nt ? acc01 : acc00);
        float s20 = 0.f, s21 = 0.f;
#pragma unroll
        for (int r = 0; r < 8; ++r) {
          s20 = fmaf(a[r], a[r], s20);
          s21 = fmaf(a[r + 8], a[r + 8], s21);
        }
        s20 += __shfl_xor(s20, 32, 64);
        s21 += __shfl_xor(s21, 32, 64);
        float i0 = 1.0f / fmaxf(sqrtf(s20), EPSN);
        float i1 = 1.0f / fmaxf(sqrtf(s21), EPSN);
#pragma unroll
        for (int r = 0; r < 8; ++r) qsum[nt][r] += a[r] * i0 + a[r + 8] * i1;
      }
    }
#pragma unroll
    for (int nt = 0; nt < 2; ++nt)
#pragma unroll
      for (int r = 0; r < 8; ++r) {
        int j = (r & 3) + ((r >> 2) << 3) + (q2 << 2);
        atomicAdd(&qbarL[j * QS + nt * 32 + px], qsum[nt][r] * (1.0f / 64.0f));
      }
  }
  __syncthreads();

  // ================= k phase =================
  acc00 = (f32x16)0.f; acc01 = (f32x16)0.f;
  acc10 = (f32x16)0.f; acc11 = (f32x16)0.f;
  PHASE((wsp + WKF_OFF));

  {
    float qb[2][8];
#pragma unroll
    for (int nt = 0; nt < 2; ++nt)
#pragma unroll
      for (int r = 0; r < 8; ++r) {
        int j = (r & 3) + ((r >> 2) << 3) + (q2 << 2);
        qb[nt][r] = qbarL[j * QS + nt * 32 + px];
      }
#pragma unroll
    for (int ot = 0; ot < 2; ++ot) {
#pragma unroll
      for (int nt = 0; nt < 2; ++nt) {
        const f32x16 a = ot ? (nt ? acc11 : acc10) : (nt ? acc01 : acc00);
        float s20 = 0.f, s21 = 0.f, sp0 = 0.f, sp1 = 0.f;
#pragma unroll
        for (int r = 0; r < 8; ++r) {
          s20 = fmaf(a[r], a[r], s20);         sp0 = fmaf(qb[nt][r], a[r], sp0);
          s21 = fmaf(a[r + 8], a[r + 8], s21); sp1 = fmaf(qb[nt][r], a[r + 8], sp1);
        }
        s20 += __shfl_xor(s20, 32, 64);
        s21 += __shfl_xor(s21, 32, 64);
        sp0 += __shfl_xor(sp0, 32, 64);
        sp1 += __shfl_xor(sp1, 32, 64);
        if (q2 == 0) {
          int m0 = wid * 4 + ot * 2;
          attnM[(nt * 32 + px) * AT + m0]     = f2bf(sp0 / fmaxf(sqrtf(s20), EPSN));
          attnM[(nt * 32 + px) * AT + m0 + 1] = f2bf(sp1 / fmaxf(sqrtf(s21), EPSN));
        }
      }
    }
  }
  __syncthreads();

  // ================= epilogue: out = x + bout + WVt @ attn =================
  {
    const int otile = wid >> 1, pxt = wid & 1;
    f32x16 e = (f32x16)0.f;
    const unsigned short* wv = wsp + WVP_OFF + (otile * 32 + px) * 64 + q2 * 8;
    const unsigned short* ab = &attnM[(pxt * 32 + px) * AT + q2 * 8];
#pragma unroll
    for (int ks = 0; ks < 4; ++ks) {
      bf16x8 av = *(const bf16x8*)(wv + ks * 16);
      bf16x8 bv = *(const bf16x8*)(ab + ks * 16);
      e = __builtin_amdgcn_mfma_f32_32x32x16_bf16(av, bv, e, 0, 0, 0);
    }
#pragma unroll
    for (int r = 0; r < 16; ++r) {
      const int o = otile * 32 + (r & 3) + ((r >> 2) << 3) + (q2 << 2);
      const int p = pxt * 32 + px;
      const int gi = (b * 256 + o) * 4096 + s0 + p;
      out[gi] = x[gi] + boutL[o] + e[r];
    }
  }
#undef PHASE
#undef COMPUTEA
#undef ISSUE
}

// =====================================================================
extern "C" void kernel_launch(void* const* d_in, const int* in_sizes, int n_in,
                              void* d_out, int out_size, void* d_ws, size_t ws_size,
                              hipStream_t stream) {
  const float* x    = (const float*)d_in[0];
  const float* pos  = (const float*)d_in[1];
  const float* wq   = (const float*)d_in[2];
  const float* bq   = (const float*)d_in[3];
  const float* wk   = (const float*)d_in[4];
  const float* bk   = (const float*)d_in[5];
  const float* v    = (const float*)d_in[6];
  const float* wout = (const float*)d_in[7];
  const float* bout = (const float*)d_in[8];
  float* out = (float*)d_out;
  unsigned short* wsp = (unsigned short*)d_ws;

  hipLaunchKernelGGL(prep_kernel, dim3(1536), dim3(256), 0, stream,
                     wq, bq, wk, bk, v, wout, wsp);
  hipLaunchKernelGGL(fused_kernel, dim3(256), dim3(1024), 0, stream,
                     x, pos, wsp, bout, out);
}